// Round 9
// baseline (999.255 us; speedup 1.0000x reference)
//
#include <hip/hip_runtime.h>

// MonoFlangerChorusModule — round 6/7/8: fixed 64-step chunks with in-register
// Jacobi-pass resolution of intra-chunk deps. One block (4 waves) per chain:
//  w0: consumer — per chunk: shuffle prev-chunk y / prefetched LDS for old
//      values, then P shuffle+fma passes (P precomputed per chunk).
//  w1/w2: meta producers (tile v): {p,n,idx1,idx2,f,x,d1,d2,wi} + pass count.
//  w3: epilogue (tile v-3): mix/clip/store.

constexpr int MAX_MIN = 441;
constexpr int MAX_LFO = 441;
constexpr int D = MAX_MIN + MAX_LFO;   // 882
constexpr int B = 32;
constexpr int C = 2;
constexpr int N = 65536;
constexpr int T = 1024;                // tile
constexpr int CHT = T / 64;            // 16 chunks per tile
constexpr int NT = N / T;              // 64 tiles
constexpr int NCH = N / 64;            // 1024 chunks total

__global__ __launch_bounds__(256)
void flanger_pass(const float* __restrict__ x,        // (B,C,N)
                  const float* __restrict__ mod_sig,  // (B,N)
                  const float* __restrict__ feedback, // (B,)
                  const float* __restrict__ mdwp,     // (B,)
                  const float* __restrict__ widthp,   // (B,)
                  const float* __restrict__ depthp,   // (B,)
                  const float* __restrict__ mixp,     // (B,)
                  float* __restrict__ out)            // (B,C,N)
{
  const int bc   = blockIdx.x;
  const int b    = bc >> 1;
  const int tid  = threadIdx.x;
  const int wv   = tid >> 6;
  const int lane = tid & 63;

  __shared__ float buf[1024];          // D=882 used; 1024 so garbage idx safe
  __shared__ uint4 q[4][T];            // meta ring (by tile & 3)
  __shared__ float it[2][T];           // interp ring (by tile & 1)
  __shared__ int   pcr[4][CHT];        // per-chunk pass count ring

  for (int i = tid; i < 1024; i += 256) buf[i] = 0.0f;

  const float fb     = feedback[b];
  const float dpv    = depthp[b];
  const float mx     = mixp[b];
  const float wscale = (float)MAX_LFO * widthp[b];  // 441*width
  const float dmin   = mdwp[b] * (float)MAX_MIN;    // mdw*441

  const float* __restrict__ xc = x + (size_t)bc * N;
  const float* __restrict__ ms = mod_sig + (size_t)b * N;
  float* __restrict__ oc = out + (size_t)bc * N;

  __syncthreads();

  // consumer persistent pipeline state (only wv==0 uses)
  uint4 mC = make_uint4(0,0,0,0), mN = make_uint4(0,0,0,0);
  float Lp = 0.0f, Ln = 0.0f;
  int Pc = 0;
  float yprev = 0.0f;

  for (int v = 0; v <= NT + 2; ++v) {
    if (wv == 1 || wv == 2) {
      // ---------------- producers: tile v ----------------
      if (v < NT) {
        const int half = wv - 1;
        uint4* __restrict__ qd = q[v & 3];
#pragma unroll
        for (int r = 0; r < 8; ++r) {
          const int i = half * 512 + r * 64 + lane;
          const int s = v * T + i;
          const float mv = ms[s];
          const float xv = xc[s];
          const float delay = wscale * mv + dmin;     // [0, 882)
          const int wi = s % D;
          float rr = (float)wi - delay + (float)D;    // (0, 2D)
          if (rr >= (float)D) rr -= (float)D;         // exact fmod here
          const float pf = floorf(rr);
          const int p = (int)pf;                      // 0..881
          const float f = rr - pf;
          const int nn = (p + 1 == D) ? 0 : p + 1;
          int dist = wi - p; if (dist <= 0) dist += D;      // d1 in [1, D]
          const int d2 = (dist == 1) ? D : dist - 1;        // slot n's distance
          const int idx1 = (lane - dist) & 63;
          const int idx2 = (lane - d2) & 63;
          qd[i] = make_uint4(
              (unsigned)p | ((unsigned)nn << 10) |
              ((unsigned)idx1 << 20) | ((unsigned)idx2 << 26),
              __float_as_uint(f), __float_as_uint(xv),
              (unsigned)dist | ((unsigned)d2 << 10) | ((unsigned)wi << 20));
          // per-chunk pass count: P = floor(63 / min over chunk of min(d1,d2))
          int h = (dist == 1) ? 1 : dist - 1;
          h = min(h, __shfl_xor(h, 32));
          h = min(h, __shfl_xor(h, 16));
          h = min(h, __shfl_xor(h, 8));
          h = min(h, __shfl_xor(h, 4));
          h = min(h, __shfl_xor(h, 2));
          h = min(h, __shfl_xor(h, 1));
          if (lane == 0) pcr[v & 3][half * 8 + r] = 63 / h; // h>=64 -> 0
        }
      }
    } else if (wv == 0) {
      // ---------------- consumer: tile tc = v-2 ----------------
      const int tc = v - 2;
      if (tc >= 0 && tc < NT) {
        if (tc == 0) {           // prime the 2-deep pipeline
          mC = q[0][lane];
          mN = q[0][64 + lane];
          Lp = buf[mC.x & 1023u];
          Ln = buf[(mC.x >> 10) & 1023u];
          Pc = pcr[0][0];
        }
        const int gbase = tc * CHT;
        for (int c = 0; c < CHT; ++c) {
          const int g = gbase + c;
          // prefetches for g+1 / g+2 (issued before this chunk's writes;
          // LDS-classified values only come from chunks <= g-1: reorder-safe)
          int g2 = g + 2; if (g2 > NCH - 1) g2 = NCH - 1;
          const uint4 mNN = q[(g2 >> 4) & 3][((g2 & 15) << 6) + lane];
          const float LpN = buf[mN.x & 1023u];
          const float LnN = buf[(mN.x >> 10) & 1023u];
          int g1 = g + 1; if (g1 > NCH - 1) g1 = NCH - 1;
          const int PcN = pcr[(g1 >> 4) & 3][g1 & 15];

          // unpack chunk g meta
          const int idx1 = (int)((mC.x >> 20) & 63u);
          const int idx2 = (int)((mC.x >> 26) & 63u);
          const float f  = __uint_as_float(mC.y);
          const float xv = __uint_as_float(mC.z);
          const int d1 = (int)(mC.w & 1023u);
          const int d2 = (int)((mC.w >> 10) & 1023u);
          const int wi = (int)((mC.w >> 20) & 1023u);

          // classify sources; prev-chunk values via shuffle of yprev
          const float b1p = __shfl(yprev, idx1, 64);
          const float b2p = __shfl(yprev, idx2, 64);
          const bool i1 = (d1 <= lane);               // intra-chunk dep
          const bool i2 = (d2 <= lane);
          const float v1f = (d1 <= lane + 64) ? b1p : Lp;  // final unless intra
          const float v2f = (d2 <= lane + 64) ? b2p : Ln;
          const float gf = 1.0f - f;
          float interp = f * v2f + gf * v1f;
          float y = xv + fb * interp;                 // exact for depth-0 lanes

          const int P = __builtin_amdgcn_readfirstlane(Pc);
          for (int t = 0; t < P; ++t) {               // depth-k exact after pass k
            const float s1 = __shfl(y, idx1, 64);
            const float s2 = __shfl(y, idx2, 64);
            const float v1 = i1 ? s1 : v1f;
            const float v2 = i2 ? s2 : v2f;
            interp = f * v2 + gf * v1;
            y = xv + fb * interp;
          }

          buf[wi] = y;                                // distinct wi per lane
          it[tc & 1][(c << 6) + lane] = interp;
          yprev = y;
          mC = mN; mN = mNN; Lp = LpN; Ln = LnN; Pc = PcN;
        }
      }
    } else {
      // ---------------- epilogue: tile te = v-3 ----------------
      const int te = v - 3;
      if (te >= 0 && te < NT) {
        const float* __restrict__ itr = it[te & 1];
        const int base = te * T;
#pragma unroll 4
        for (int r = 0; r < CHT; ++r) {
          const int i = r * 64 + lane;
          const float xv = xc[base + i];
          const float interp = itr[i];
          const float o = xv + dpv * interp;
          float res = (1.0f - mx) * xv + mx * o;
          res = fminf(fmaxf(res, -1.0f), 1.0f);
          oc[base + i] = res;
        }
      }
    }
    __syncthreads();
  }
}

extern "C" void kernel_launch(void* const* d_in, const int* in_sizes, int n_in,
                              void* d_out, int out_size, void* d_ws, size_t ws_size,
                              hipStream_t stream) {
  const float* x        = (const float*)d_in[0];
  const float* mod_sig  = (const float*)d_in[1];
  const float* feedback = (const float*)d_in[2];
  const float* mdw      = (const float*)d_in[3];
  const float* width    = (const float*)d_in[4];
  const float* depth    = (const float*)d_in[5];
  const float* mix      = (const float*)d_in[6];
  float* out = (float*)d_out;

  flanger_pass<<<dim3(B * C), dim3(256), 0, stream>>>(
      x, mod_sig, feedback, mdw, width, depth, mix, out);
}

// Round 10
// 519.760 us; speedup vs baseline: 1.9225x; 1.9225x over previous
//
#include <hip/hip_runtime.h>

// MonoFlangerChorusModule — round 9: fixed 64-step chunks; intra-chunk deps
// resolved by Jacobi passes that run EXACTLY true-depth times (ballot
// convergence mask), with the initial gather unified through LDS.
//  w0: consumer; w1/w2: meta producers (tile v); w3: epilogue (tile v-3).

constexpr int MAX_MIN = 441;
constexpr int MAX_LFO = 441;
constexpr int D = MAX_MIN + MAX_LFO;   // 882
constexpr int B = 32;
constexpr int C = 2;
constexpr int N = 65536;
constexpr int T = 1024;                // tile
constexpr int CHT = T / 64;            // 16 chunks per tile
constexpr int NT = N / T;              // 64 tiles
constexpr int NCH = N / 64;            // 1024 chunks total

__global__ __launch_bounds__(256)
void flanger_conv(const float* __restrict__ x,        // (B,C,N)
                  const float* __restrict__ mod_sig,  // (B,N)
                  const float* __restrict__ feedback, // (B,)
                  const float* __restrict__ mdwp,     // (B,)
                  const float* __restrict__ widthp,   // (B,)
                  const float* __restrict__ depthp,   // (B,)
                  const float* __restrict__ mixp,     // (B,)
                  float* __restrict__ out)            // (B,C,N)
{
  const int bc   = blockIdx.x;
  const int b    = bc >> 1;
  const int tid  = threadIdx.x;
  const int wv   = tid >> 6;
  const int lane = tid & 63;

  __shared__ float buf[1024];          // D=882 used; zero-init
  __shared__ uint4 q[4][T];            // meta ring (by tile & 3)
  __shared__ float it[2][T];           // interp ring (by tile & 1)

  for (int i = tid; i < 1024; i += 256) buf[i] = 0.0f;

  const float fb     = feedback[b];
  const float dpv    = depthp[b];
  const float mixv   = mixp[b];
  const float wscale = (float)MAX_LFO * widthp[b];  // 441*width
  const float dmin   = mdwp[b] * (float)MAX_MIN;    // mdw*441

  const float* __restrict__ xc = x + (size_t)bc * N;
  const float* __restrict__ ms = mod_sig + (size_t)b * N;
  float* __restrict__ oc = out + (size_t)bc * N;

  __syncthreads();

  // consumer pipeline regs (wv==0 only)
  uint4 mC = make_uint4(0,0,0,0), mN = make_uint4(0,0,0,0);

  for (int v = 0; v <= NT + 2; ++v) {
    if (wv == 1 || wv == 2) {
      // ---------------- producers: tile v ----------------
      if (v < NT) {
        const int half = wv - 1;
        uint4* __restrict__ qd = q[v & 3];
#pragma unroll
        for (int r = 0; r < 8; ++r) {
          const int i = half * 512 + r * 64 + lane;
          const int s = v * T + i;
          const float mv = ms[s];
          const float xv = xc[s];
          const float delay = wscale * mv + dmin;     // [0, 882)
          const int wi = s % D;
          float rr = (float)wi - delay + (float)D;    // (0, 2D)
          if (rr >= (float)D) rr -= (float)D;         // exact fmod here
          const float pf = floorf(rr);
          const int p = (int)pf;                      // 0..881
          const float f = rr - pf;
          const int nn = (p + 1 == D) ? 0 : p + 1;
          int dist = wi - p; if (dist <= 0) dist += D;      // d1 in [1, D]
          const int d2 = (dist == 1) ? D : dist - 1;        // slot n's distance
          const int idx1 = (lane - dist) & 63;
          const int idx2 = (lane - d2) & 63;
          qd[i] = make_uint4(
              (unsigned)p | ((unsigned)nn << 10) |
              ((unsigned)idx1 << 20) | ((unsigned)idx2 << 26),
              __float_as_uint(f), __float_as_uint(xv),
              (unsigned)dist | ((unsigned)d2 << 10) | ((unsigned)wi << 20));
        }
      }
    } else if (wv == 0) {
      // ---------------- consumer: tile tc = v-2 ----------------
      const int tc = v - 2;
      if (tc >= 0 && tc < NT) {
        if (tc == 0) {                 // prime 2-deep meta pipeline
          mC = q[0][lane];
          mN = q[0][64 + lane];
        }
        const int gbase = tc * CHT;
        for (int c = 0; c < CHT; ++c) {
          const int g = gbase + c;
          // critical LDS gather first (sees all prev-chunk writes)
          const unsigned mx0 = mC.x;
          const int p  = (int)(mx0 & 1023u);
          const int nn = (int)((mx0 >> 10) & 1023u);
          const float pv = buf[p];
          const float nv = buf[nn];
          // prefetch chunk g+2 meta (ready when it becomes mC)
          int g2 = g + 2; if (g2 > NCH - 1) g2 = NCH - 1;
          const uint4 mNN = q[(g2 >> 4) & 3][((g2 & 15) << 6) + lane];

          const float f  = __uint_as_float(mC.y);
          const float xv = __uint_as_float(mC.z);
          const int d1 = (int)(mC.w & 1023u);
          const int d2 = (int)((mC.w >> 10) & 1023u);
          const int wi = (int)((mC.w >> 20) & 1023u);
          const int ib1 = (int)((mx0 >> 18) & 252u);   // idx1*4 (bpermute addr)
          const int ib2 = (int)((mx0 >> 24) & 252u);   // idx2*4
          const bool ex1 = d1 > lane;                  // dep precedes chunk
          const bool ex2 = d2 > lane;
          const float gf = 1.0f - f;

          float interp = f * nv + gf * pv;             // exact if ex1&&ex2
          float y = xv + fb * interp;

          unsigned long long mask = __ballot(ex1 && ex2);
          while (~mask) {                              // until all lanes final
            const float s1 = __int_as_float(
                __builtin_amdgcn_ds_bpermute(ib1, __float_as_int(y)));
            const float s2 = __int_as_float(
                __builtin_amdgcn_ds_bpermute(ib2, __float_as_int(y)));
            const float v1 = ex1 ? pv : s1;
            const float v2 = ex2 ? nv : s2;
            interp = f * v2 + gf * v1;
            y = xv + fb * interp;
            const bool f1 = ex1 || ((mask >> (ib1 >> 2)) & 1ull);
            const bool f2 = ex2 || ((mask >> (ib2 >> 2)) & 1ull);
            mask = __ballot(f1 && f2);                 // monotone; <=depth iters
          }

          buf[wi] = y;                                 // distinct wi per lane
          it[tc & 1][(c << 6) + lane] = interp;
          mC = mN; mN = mNN;
        }
      }
    } else {
      // ---------------- epilogue: tile te = v-3 ----------------
      const int te = v - 3;
      if (te >= 0 && te < NT) {
        const float* __restrict__ itr = it[te & 1];
        const int base = te * T;
#pragma unroll 4
        for (int r = 0; r < CHT; ++r) {
          const int i = r * 64 + lane;
          const float xv = xc[base + i];
          const float interp = itr[i];
          const float o = xv + dpv * interp;
          float res = (1.0f - mixv) * xv + mixv * o;
          res = fminf(fmaxf(res, -1.0f), 1.0f);
          oc[base + i] = res;
        }
      }
    }
    __syncthreads();
  }
}

extern "C" void kernel_launch(void* const* d_in, const int* in_sizes, int n_in,
                              void* d_out, int out_size, void* d_ws, size_t ws_size,
                              hipStream_t stream) {
  const float* x        = (const float*)d_in[0];
  const float* mod_sig  = (const float*)d_in[1];
  const float* feedback = (const float*)d_in[2];
  const float* mdw      = (const float*)d_in[3];
  const float* width    = (const float*)d_in[4];
  const float* depth    = (const float*)d_in[5];
  const float* mix      = (const float*)d_in[6];
  float* out = (float*)d_out;

  flanger_conv<<<dim3(B * C), dim3(256), 0, stream>>>(
      x, mod_sig, feedback, mdw, width, depth, mix, out);
}